// Round 6
// baseline (219.439 us; speedup 1.0000x reference)
//
#include <hip/hip_runtime.h>
#include <hip/hip_bf16.h>
#include <cstdint>
#include <cstddef>

#define DEVI __device__ __forceinline__

static constexpr int SEQ = 2048;
static constexpr int DM  = 1024;
static constexpr int NH  = 16;
static constexpr int HD  = 64;
static constexpr int NTOK = 2 * SEQ;
static constexpr int NBUCKET = 257;
static constexpr float LOG2E = 1.44269504088896f;

typedef __attribute__((ext_vector_type(8))) short bf16x8;
typedef __attribute__((ext_vector_type(4))) float f32x4;
typedef __attribute__((ext_vector_type(16))) float f32x16;
#define MFMA16(a, b, c) __builtin_amdgcn_mfma_f32_16x16x32_bf16((a), (b), (c), 0, 0, 0)
#define MFMA32(a, b, c) __builtin_amdgcn_mfma_f32_32x32x16_bf16((a), (b), (c), 0, 0, 0)

DEVI float bf1(uint16_t u)  { return __uint_as_float(((uint32_t)u) << 16); }
DEVI uint16_t f2bf(float f) {
    uint32_t x = __float_as_uint(f);
    x += 0x7fffu + ((x >> 16) & 1u);   // RTNE
    return (uint16_t)(x >> 16);
}
DEVI bf16x8 ld_frag(const uint16_t* p) {
    union { uint4 u; bf16x8 f; } c;
    c.u = *(const uint4*)p;
    return c.f;
}
DEVI void gld16(const uint16_t* g, uint16_t* l) {
    __builtin_amdgcn_global_load_lds(
        (const __attribute__((address_space(1))) uint32_t*)g,
        (__attribute__((address_space(3))) uint32_t*)l, 16, 0, 0);
}
DEVI uint32_t xsw32(uint32_t v) { return (uint32_t)__shfl_xor((int)v, 32, 64); }

// ============================================================
__global__ void sniff_kernel(const uint16_t* __restrict__ x, int* __restrict__ flag)
{
    int bad = 0;
    for (int i = threadIdx.x; i < 512; i += 64) {
        const float v = bf1(x[i]);
        if (!(fabsf(v) < 64.0f)) bad = 1;
    }
    const unsigned long long m = __ballot(bad);
    if (threadIdx.x == 0) *flag = (m != 0ull) ? 1 : 0;
}

// ============================================================
__global__ __launch_bounds__(256)
void convert_kernel(const void* __restrict__ x, const void* __restrict__ Wq,
                    const void* __restrict__ Wk, const void* __restrict__ Wv,
                    const void* __restrict__ Wo, const void* __restrict__ bq,
                    const void* __restrict__ bk, const void* __restrict__ bv,
                    const void* __restrict__ bo, uint16_t* __restrict__ dst,
                    const int* __restrict__ flagp)
{
    const bool f32in = (*flagp != 0);
    const size_t M4 = 4194304, M1 = 1048576;
    const size_t e = ((size_t)blockIdx.x * 256 + threadIdx.x) * 8;
    const void* src; size_t off;
    if      (e < M4)                 { src = x;  off = e; }
    else if (e < M4 + M1)            { src = Wq; off = e - M4; }
    else if (e < M4 + 2*M1)          { src = Wk; off = e - M4 - M1; }
    else if (e < M4 + 3*M1)          { src = Wv; off = e - M4 - 2*M1; }
    else if (e < M4 + 4*M1)          { src = Wo; off = e - M4 - 3*M1; }
    else if (e < M4 + 4*M1 + 1024)   { src = bq; off = e - M4 - 4*M1; }
    else if (e < M4 + 4*M1 + 2048)   { src = bk; off = e - M4 - 4*M1 - 1024; }
    else if (e < M4 + 4*M1 + 3072)   { src = bv; off = e - M4 - 4*M1 - 2048; }
    else                             { src = bo; off = e - M4 - 4*M1 - 3072; }
    if (f32in) {
        const float4 a = *(const float4*)((const float*)src + off);
        const float4 b = *(const float4*)((const float*)src + off + 4);
        uint4 o;
        o.x = (uint32_t)f2bf(a.x) | ((uint32_t)f2bf(a.y) << 16);
        o.y = (uint32_t)f2bf(a.z) | ((uint32_t)f2bf(a.w) << 16);
        o.z = (uint32_t)f2bf(b.x) | ((uint32_t)f2bf(b.y) << 16);
        o.w = (uint32_t)f2bf(b.z) | ((uint32_t)f2bf(b.w) << 16);
        *(uint4*)(dst + e) = o;
    } else {
        *(uint4*)(dst + e) = *(const uint4*)((const uint16_t*)src + off);
    }
}

// ============================================================
// Fused QKV MFMA GEMM. Q output PRESCALED by 0.125*log2(e) so attention
// can use exp2 directly (saves one v_mul per score).
// ============================================================
__global__ __launch_bounds__(256)
void gemm_qkv(const uint16_t* __restrict__ xc, const uint16_t* __restrict__ Wqkv,
              const uint16_t* __restrict__ bqkv,
              uint16_t* __restrict__ Qw, uint16_t* __restrict__ Kw,
              uint16_t* __restrict__ Vt)
{
    __shared__ uint16_t As[128 * 32];
    __shared__ uint16_t Bs[128 * 32];
    const int tid = threadIdx.x, bx = blockIdx.x;
    const int lane = tid & 63, wave = tid >> 6;
    const int ln = lane & 15, quad = lane >> 4;
    const int wm = (wave & 1) * 64, wn = (wave >> 1) * 64;

    const uint16_t *Ab, *Bb;
    int bm, bn, vor;
    if (bx < 512) {
        vor = 0; bm = (bx >> 4) * 128; bn = (bx & 15) * 128;
        Ab = xc + (size_t)bm * DM;  Bb = Wqkv + (size_t)bn * DM;
    } else {
        vor = 1; const int b2 = bx - 512; bm = (b2 >> 5) * 128; bn = (b2 & 31) * 128;
        Ab = Wqkv + (size_t)(2048 + bm) * DM;  Bb = xc + (size_t)bn * DM;
    }

    f32x4 acc[4][4];
    #pragma unroll
    for (int i = 0; i < 4; ++i)
        #pragma unroll
        for (int j = 0; j < 4; ++j) acc[i][j] = (f32x4){0.f, 0.f, 0.f, 0.f};

    const int s0 = tid, s1 = 256 + tid;
    const uint16_t* ga0 = Ab + (size_t)(s0 >> 2) * DM + (s0 & 3) * 8;
    const uint16_t* ga1 = Ab + (size_t)(s1 >> 2) * DM + (s1 & 3) * 8;
    const uint16_t* gb0 = Bb + (size_t)(s0 >> 2) * DM + (s0 & 3) * 8;
    const uint16_t* gb1 = Bb + (size_t)(s1 >> 2) * DM + (s1 & 3) * 8;

    for (int k0 = 0; k0 < DM; k0 += 32) {
        __syncthreads();
        gld16(ga0 + k0, &As[s0 * 8]);
        gld16(ga1 + k0, &As[s1 * 8]);
        gld16(gb0 + k0, &Bs[s0 * 8]);
        gld16(gb1 + k0, &Bs[s1 * 8]);
        __syncthreads();

        bf16x8 af[4], bfr[4];
        #pragma unroll
        for (int t = 0; t < 4; ++t) {
            af[t]  = ld_frag(&As[(wm + t * 16 + ln) * 32 + quad * 8]);
            bfr[t] = ld_frag(&Bs[(wn + t * 16 + ln) * 32 + quad * 8]);
        }
        #pragma unroll
        for (int ti = 0; ti < 4; ++ti)
            #pragma unroll
            for (int tj = 0; tj < 4; ++tj)
                acc[ti][tj] = MFMA16(af[ti], bfr[tj], acc[ti][tj]);
    }

    if (!vor) {
        #pragma unroll
        for (int tj = 0; tj < 4; ++tj) {
            const int c = bn + wn + tj * 16 + ln;
            const int mat = c >> 10, h = (c >> 6) & 15, hd = c & 63;
            uint16_t* dstp = mat ? Kw : Qw;
            const float scale = mat ? 1.0f : (0.125f * LOG2E);
            const float bb = bf1(bqkv[c]);
            #pragma unroll
            for (int ti = 0; ti < 4; ++ti)
                #pragma unroll
                for (int r = 0; r < 4; ++r) {
                    const int row = bm + wm + ti * 16 + quad * 4 + r;
                    const int b = row >> 11, s = row & 2047;
                    dstp[(((size_t)b * NH + h) * SEQ + s) * HD + hd] =
                        f2bf((acc[ti][tj][r] + bb) * scale);
                }
        }
    } else {
        #pragma unroll
        for (int ti = 0; ti < 4; ++ti)
            #pragma unroll
            for (int r = 0; r < 4; ++r) {
                const int f = bm + wm + ti * 16 + quad * 4 + r;
                const int h = f >> 6, hd = f & 63;
                const float bb = bf1(bqkv[2048 + f]);
                #pragma unroll
                for (int tj = 0; tj < 4; ++tj) {
                    const int t = bn + wn + tj * 16 + ln;
                    const int b = t >> 11, s = t & 2047;
                    Vt[(((size_t)b * NH + h) * HD + hd) * SEQ + s] = f2bf(acc[ti][tj][r] + bb);
                }
            }
    }
}

// ============================================================
// Output projection: out = Cw · Woc^T + bo. 128x64 tiles -> 512 blocks.
// ============================================================
__global__ __launch_bounds__(256)
void gemm_out(const uint16_t* __restrict__ Cw, const uint16_t* __restrict__ Woc,
              const uint16_t* __restrict__ boc, void* __restrict__ out,
              const int* __restrict__ flagp)
{
    __shared__ uint16_t As[128 * 32];
    __shared__ uint16_t Bs[64 * 32];
    const int tid = threadIdx.x, bx = blockIdx.x;
    const int lane = tid & 63, wave = tid >> 6;
    const int ln = lane & 15, quad = lane >> 4;
    const int wm = (wave & 1) * 64, wn = (wave >> 1) * 32;
    const int bm = (bx >> 4) * 128, bn = (bx & 15) * 64;
    const uint16_t* Ab = Cw + (size_t)bm * DM;
    const uint16_t* Bb = Woc + (size_t)bn * DM;

    f32x4 acc[4][2];
    #pragma unroll
    for (int i = 0; i < 4; ++i)
        #pragma unroll
        for (int j = 0; j < 2; ++j) acc[i][j] = (f32x4){0.f, 0.f, 0.f, 0.f};

    const int s0 = tid, s1 = 256 + tid;
    const uint16_t* ga0 = Ab + (size_t)(s0 >> 2) * DM + (s0 & 3) * 8;
    const uint16_t* ga1 = Ab + (size_t)(s1 >> 2) * DM + (s1 & 3) * 8;
    const uint16_t* gb0 = Bb + (size_t)(s0 >> 2) * DM + (s0 & 3) * 8;

    for (int k0 = 0; k0 < DM; k0 += 32) {
        __syncthreads();
        gld16(ga0 + k0, &As[s0 * 8]);
        gld16(ga1 + k0, &As[s1 * 8]);
        gld16(gb0 + k0, &Bs[s0 * 8]);
        __syncthreads();

        bf16x8 af[4], bfr[2];
        #pragma unroll
        for (int t = 0; t < 4; ++t)
            af[t] = ld_frag(&As[(wm + t * 16 + ln) * 32 + quad * 8]);
        #pragma unroll
        for (int t = 0; t < 2; ++t)
            bfr[t] = ld_frag(&Bs[(wn + t * 16 + ln) * 32 + quad * 8]);
        #pragma unroll
        for (int ti = 0; ti < 4; ++ti)
            #pragma unroll
            for (int tj = 0; tj < 2; ++tj)
                acc[ti][tj] = MFMA16(af[ti], bfr[tj], acc[ti][tj]);
    }

    const bool f32o = (*flagp != 0);
    #pragma unroll
    for (int tj = 0; tj < 2; ++tj) {
        const int c = bn + wn + tj * 16 + ln;
        const float bb = bf1(boc[c]);
        #pragma unroll
        for (int ti = 0; ti < 4; ++ti)
            #pragma unroll
            for (int r = 0; r < 4; ++r) {
                const int row = bm + wm + ti * 16 + quad * 4 + r;
                const float v = acc[ti][tj][r] + bb;
                if (f32o) ((float*)out)[(size_t)row * DM + c] = v;
                else      ((uint16_t*)out)[(size_t)row * DM + c] = f2bf(v);
            }
    }
}

// ============================================================
// Flash-style MFMA attention v12b: DIAGNOSTIC variant of v12.
// v12 (permlane-asm P redistribution) failed absmax 2.88 (key-scramble
// signature). All layouts re-derived and self-consistent; the one
// unverifiable primitive was the raw `v_permlane32_swap_b32` asm
// (polarity/codegen). This version implements the IDENTICAL logical
// permutation with portable primitives only:
//   __shfl_xor(.,32) partner exchange + RTNE f2bf packing + hi?: selects.
// Everything else byte-identical to v12.
//   PASS  -> permlane asm was the bug; re-accelerate next round.
//   FAIL  -> MFMA32 layout model wrong; revert to v11 base.
// ============================================================
#define PK2(a, b) ((uint32_t)f2bf(a) | ((uint32_t)f2bf(b) << 16))

// pa element j of lane (l31,hi) := P[q=l31][key_base + hi*8 + j]
// from sa[r] = P[q=l31][key_base + (r&3)+8*(r>>2)+4*hi].
#define P_BUILD(SA, PA_LO, PA_HI)                                              \
  do {                                                                         \
    const uint32_t c0_ = PK2((SA)[0], (SA)[1]);                                \
    const uint32_t c1_ = PK2((SA)[2], (SA)[3]);                                \
    const uint32_t c2_ = PK2((SA)[4], (SA)[5]);                                \
    const uint32_t c3_ = PK2((SA)[6], (SA)[7]);                                \
    const uint32_t c4_ = PK2((SA)[8], (SA)[9]);                                \
    const uint32_t c5_ = PK2((SA)[10], (SA)[11]);                              \
    const uint32_t c6_ = PK2((SA)[12], (SA)[13]);                              \
    const uint32_t c7_ = PK2((SA)[14], (SA)[15]);                              \
    const uint32_t p0_ = xsw32(c0_), p1_ = xsw32(c1_);                         \
    const uint32_t p2_ = xsw32(c2_), p3_ = xsw32(c3_);                         \
    const uint32_t p4_ = xsw32(c4_), p5_ = xsw32(c5_);                         \
    const uint32_t p6_ = xsw32(c6_), p7_ = xsw32(c7_);                         \
    union { uint32_t u[4]; bf16x8 f; } lo_, hi_;                               \
    lo_.u[0] = hi ? p2_ : c0_;  lo_.u[1] = hi ? p3_ : c1_;                     \
    lo_.u[2] = hi ? c2_ : p0_;  lo_.u[3] = hi ? c3_ : p1_;                     \
    hi_.u[0] = hi ? p6_ : c4_;  hi_.u[1] = hi ? p7_ : c5_;                     \
    hi_.u[2] = hi ? c6_ : p4_;  hi_.u[3] = hi ? c7_ : p5_;                     \
    (PA_LO) = lo_.f; (PA_HI) = hi_.f;                                          \
  } while (0)

#define ATTN_COMPUTE(K0, KSB, VSB)                                             \
  do {                                                                         \
    const int mode_ = ((K0) >= q0 + 256) ? 0 : (((K0) + 192 <= q0) ? 2 : 1);   \
    bf16x8 kf_[2][4], vf_[2][4];                                               \
    _Pragma("unroll")                                                          \
    for (int kb = 0; kb < 2; ++kb)                                             \
      _Pragma("unroll")                                                        \
      for (int ds = 0; ds < 4; ++ds)                                           \
        kf_[kb][ds] = ld_frag((KSB) + kfo[kb][ds]);                            \
    _Pragma("unroll")                                                          \
    for (int db = 0; db < 2; ++db)                                             \
      _Pragma("unroll")                                                        \
      for (int kc = 0; kc < 4; ++kc)                                           \
        vf_[db][kc] = ld_frag((VSB) + vfo[db][kc]);                            \
    f32x16 sa0, sa1;                                                           \
    {                                                                          \
      const float binit_ = (mode_ == 0) ? bneg : ((mode_ == 2) ? bpos : 0.f);  \
      _Pragma("unroll")                                                        \
      for (int r = 0; r < 16; ++r) { sa0[r] = binit_; sa1[r] = binit_; }       \
    }                                                                          \
    _Pragma("unroll")                                                          \
    for (int ds = 0; ds < 4; ++ds) {                                           \
      sa0 = MFMA32(kf_[0][ds], qb[ds], sa0);                                   \
      sa1 = MFMA32(kf_[1][ds], qb[ds], sa1);                                   \
    }                                                                          \
    if (mode_ == 1) {                                                          \
      const int iq0_ = q0 + wave * 32 + l31 + 128 - (K0) - 4 * hi;             \
      _Pragma("unroll")                                                        \
      for (int r = 0; r < 16; ++r) {                                           \
        const int ko_ = (r & 3) + 8 * (r >> 2);                                \
        const int x0_ = max(0, min(256, iq0_ - ko_));                          \
        const int x1_ = max(0, min(256, iq0_ - 32 - ko_));                     \
        sa0[r] += bias_s[x0_];                                                 \
        sa1[r] += bias_s[x1_];                                                 \
      }                                                                        \
    }                                                                          \
    _Pragma("unroll")                                                          \
    for (int r = 0; r < 16; ++r) {                                             \
      sa0[r] = __builtin_amdgcn_exp2f(sa0[r]);                                 \
      sa1[r] = __builtin_amdgcn_exp2f(sa1[r]);                                 \
    }                                                                          \
    bf16x8 pa_[4];                                                             \
    P_BUILD(sa0, pa_[0], pa_[1]);                                              \
    P_BUILD(sa1, pa_[2], pa_[3]);                                              \
    _Pragma("unroll")                                                          \
    for (int kc = 0; kc < 4; ++kc) {                                           \
      lf    = MFMA32(pa_[kc], onef, lf);                                       \
      o2[0] = MFMA32(pa_[kc], vf_[0][kc], o2[0]);                              \
      o2[1] = MFMA32(pa_[kc], vf_[1][kc], o2[1]);                              \
    }                                                                          \
  } while (0)

__global__ __launch_bounds__(256, 2)
void attn_mfma(const uint16_t* __restrict__ Q, const uint16_t* __restrict__ K,
               const uint16_t* __restrict__ Vt, const void* __restrict__ rel,
               uint16_t* __restrict__ ctx, const int* __restrict__ flagp)
{
    __shared__ alignas(16) uint16_t Ks[2][64 * 64];   // [buf][key][d], swizzled, 16 KB
    __shared__ alignas(16) uint16_t Vls[2][64 * 64];  // [buf][d][key], swizzled, 16 KB
    __shared__ float bias_s[NBUCKET];                 // bias*log2e - C8

    const bool f32in = (*flagp != 0);
    const int tid = threadIdx.x, wave = tid >> 6, lane = tid & 63;
    const int l31 = lane & 31, hi = lane >> 5;

    const int blk = blockIdx.x;                         // 512 blocks
    const int bh = (blk & 7) * 4 + ((blk >> 3) & 3);    // XCD-aware bh spread
    const int qt = blk >> 5;                            // 16 q-tiles of 128 rows
    const int b = bh >> 4, h = bh & 15;
    const int q0 = qt * 128;

    const float C8 = 8.0f * LOG2E;   // fixed-max shift (in exp2 domain)
    for (int i = tid; i < NBUCKET; i += 256) {
        const float bv = f32in ? ((const float*)rel)[i * NH + h]
                               : bf1(((const uint16_t*)rel)[i * NH + h]);
        bias_s[i] = bv * LOG2E - C8;
    }

    // Q B-frags (32x32x16 B-layout): lane holds col q = l31, k = hi*8+j
    bf16x8 qb[4];
    {
        const uint16_t* qp = Q + ((size_t)bh * SEQ + q0 + wave * 32 + l31) * HD;
        #pragma unroll
        for (int ds = 0; ds < 4; ++ds)
            qb[ds] = ld_frag(qp + ds * 16 + hi * 8);
    }

    // ones B-frag for l = P · 1 (reads the same bf16 pa frags as PV)
    union { uint4 u; bf16x8 f; } onec;
    onec.u = (uint4){0x3F803F80u, 0x3F803F80u, 0x3F803F80u, 0x3F803F80u};
    const bf16x8 onef = onec.f;

    f32x16 o2[2], lf;
    #pragma unroll
    for (int r = 0; r < 16; ++r) { o2[0][r] = 0.f; o2[1][r] = 0.f; lf[r] = 0.f; }

    // ---- staging: 256 threads x 2 segments x 16 B = one 64x128B tile ----
    const int s0_ = tid, s1_ = tid + 256;
    const int r0_ = s0_ >> 3, c0s_ = (s0_ & 7) ^ (r0_ & 7);
    const int r1_ = s1_ >> 3, c1s_ = (s1_ & 7) ^ (r1_ & 7);
    const int koff0 = r0_ * HD + c0s_ * 8,  koff1 = r1_ * HD + c1s_ * 8;
    const int voff0 = r0_ * SEQ + c0s_ * 8, voff1 = r1_ * SEQ + c1s_ * 8;
    uint16_t* const kd00 = &Ks[0][s0_ * 8];
    uint16_t* const kd01 = &Ks[0][s1_ * 8];
    uint16_t* const kd10 = &Ks[1][s0_ * 8];
    uint16_t* const kd11 = &Ks[1][s1_ * 8];
    uint16_t* const vd00 = &Vls[0][s0_ * 8];
    uint16_t* const vd01 = &Vls[0][s1_ * 8];
    uint16_t* const vd10 = &Vls[1][s0_ * 8];
    uint16_t* const vd11 = &Vls[1][s1_ * 8];

    const uint16_t* kg = K  + (size_t)bh * SEQ * HD;   // +64*HD per tile
    const uint16_t* vg = Vt + (size_t)bh * HD * SEQ;   // +64 per tile

    // ---- k0-invariant LDS frag offsets (row&7 == l31&7 for both) ----
    const int swz = l31 & 7;
    int kfo[2][4], vfo[2][4];
    #pragma unroll
    for (int kb = 0; kb < 2; ++kb)
        #pragma unroll
        for (int ds = 0; ds < 4; ++ds)
            kfo[kb][ds] = (kb * 32 + l31) * 64 + ((ds * 2 + hi) ^ swz) * 8;
    #pragma unroll
    for (int db = 0; db < 2; ++db)
        #pragma unroll
        for (int kc = 0; kc < 4; ++kc)
            vfo[db][kc] = (db * 32 + l31) * 64 + ((kc * 2 + hi) ^ swz) * 8;

    // ---- prologue: stage tile 0 into buf0 ----
    gld16(kg + koff0, kd00); gld16(kg + koff1, kd01);
    gld16(vg + voff0, vd00); gld16(vg + voff1, vd01);
    kg += 64 * HD; vg += 64;
    __syncthreads();   // drains stage-0 + bias_s fill
    const float bneg = bias_s[0], bpos = bias_s[256];

    // ---- main loop: 16 double-iters, 1 barrier per k-tile ----
    for (int t = 0; t < 16; ++t) {
        // phase A: tile 2t in buf0; prefetch tile 2t+1 -> buf1
        gld16(kg + koff0, kd10); gld16(kg + koff1, kd11);
        gld16(vg + voff0, vd10); gld16(vg + voff1, vd11);
        kg += 64 * HD; vg += 64;
        ATTN_COMPUTE(t * 128, &Ks[0][0], &Vls[0][0]);
        __syncthreads();   // vmcnt(0) drain lands ~full phase after issue

        // phase B: tile 2t+1 in buf1; prefetch tile 2t+2 -> buf0
        if (t < 15) {
            gld16(kg + koff0, kd00); gld16(kg + koff1, kd01);
            gld16(vg + voff0, vd00); gld16(vg + voff1, vd01);
            kg += 64 * HD; vg += 64;
        }
        ATTN_COMPUTE(t * 128 + 64, &Ks[1][0], &Vls[1][0]);
        __syncthreads();
    }

    // ---- epilogue: lf[r] and o2[db][r] share the q=crow(r,hi) layout ----
    #pragma unroll
    for (int r = 0; r < 16; ++r) {
        const float inv = 1.0f / lf[r];
        const int qq = q0 + wave * 32 + (r & 3) + 8 * (r >> 2) + 4 * hi;
        #pragma unroll
        for (int db = 0; db < 2; ++db)
            ctx[(((size_t)b * SEQ + qq) * NH + h) * HD + db * 32 + l31] =
                f2bf(o2[db][r] * inv);
    }
}

// ============================================================
extern "C" void kernel_launch(void* const* d_in, const int* in_sizes, int n_in,
                              void* d_out, int out_size, void* d_ws, size_t ws_size,
                              hipStream_t stream)
{
    const void* x   = d_in[0];
    const void* Wq  = d_in[1];
    const void* bq  = d_in[2];
    const void* Wk  = d_in[3];
    const void* bk  = d_in[4];
    const void* Wv  = d_in[5];
    const void* bv  = d_in[6];
    const void* Wo  = d_in[7];
    const void* bo  = d_in[8];
    const void* rel = d_in[9];

    const size_t M4 = 4194304, M1 = 1048576;
    uint16_t* ws16 = (uint16_t*)d_ws;
    uint16_t* xc   = ws16;                    // 4M; reused as Cw after QKV GEMM
    uint16_t* Wqkv = ws16 + M4;               // 3M  [Wq;Wk;Wv]
    uint16_t* Woc  = ws16 + M4 + 3 * M1;      // 1M
    uint16_t* bqkv = ws16 + M4 + 4 * M1;      // 3072 [bq;bk;bv]
    uint16_t* boc  = bqkv + 3072;             // 1024
    uint16_t* Qw   = ws16 + M4 + 4 * M1 + 8192;
    uint16_t* Kw   = Qw + M4;
    uint16_t* Vt   = Kw + M4;
    int* flag = (int*)(Vt + M4);
    uint16_t* Cw = xc;   // overlay: xc dead after gemm_qkv

    sniff_kernel<<<1, 64, 0, stream>>>((const uint16_t*)x, flag);
    convert_kernel<<<4098, 256, 0, stream>>>(x, Wq, Wk, Wv, Wo, bq, bk, bv, bo,
                                             ws16, flag);
    gemm_qkv<<<768, 256, 0, stream>>>(xc, Wqkv, bqkv, Qw, Kw, Vt);
    attn_mfma<<<512, 256, 0, stream>>>(Qw, Kw, Vt, rel, Cw, flag);
    gemm_out<<<512, 256, 0, stream>>>(Cw, Woc, boc, d_out, flag);
}

// Round 7
// 205.323 us; speedup vs baseline: 1.0688x; 1.0688x over previous
//
#include <hip/hip_runtime.h>
#include <hip/hip_bf16.h>
#include <cstdint>
#include <cstddef>

#define DEVI __device__ __forceinline__

static constexpr int SEQ = 2048;
static constexpr int DM  = 1024;
static constexpr int NH  = 16;
static constexpr int HD  = 64;
static constexpr int NTOK = 2 * SEQ;
static constexpr int NBUCKET = 257;
static constexpr float LOG2E = 1.44269504088896f;

typedef __attribute__((ext_vector_type(8))) short bf16x8;
typedef __attribute__((ext_vector_type(4))) float f32x4;
typedef __attribute__((ext_vector_type(16))) float f32x16;
typedef __attribute__((ext_vector_type(2))) unsigned int uint32x2;
#define MFMA16(a, b, c) __builtin_amdgcn_mfma_f32_16x16x32_bf16((a), (b), (c), 0, 0, 0)
#define MFMA32(a, b, c) __builtin_amdgcn_mfma_f32_32x32x16_bf16((a), (b), (c), 0, 0, 0)

DEVI float bf1(uint16_t u)  { return __uint_as_float(((uint32_t)u) << 16); }
DEVI uint16_t f2bf(float f) {
    uint32_t x = __float_as_uint(f);
    x += 0x7fffu + ((x >> 16) & 1u);   // RTNE
    return (uint16_t)(x >> 16);
}
DEVI bf16x8 ld_frag(const uint16_t* p) {
    union { uint4 u; bf16x8 f; } c;
    c.u = *(const uint4*)p;
    return c.f;
}
DEVI void gld16(const uint16_t* g, uint16_t* l) {
    __builtin_amdgcn_global_load_lds(
        (const __attribute__((address_space(1))) uint32_t*)g,
        (__attribute__((address_space(3))) uint32_t*)l, 16, 0, 0);
}
// Guide-verified T12 primitives (m214v22): asm cvt_pk (D.lo=bf16(S0),
// D.hi=bf16(S1)) + BUILTIN permlane32_swap (r[0]=new first arg: lanes<32
// keep own, lanes>=32 take b[lane-32]; r[1]=new second arg).
DEVI uint32_t cvt_pk_bf16(float lo, float hi) {
    uint32_t r;
    asm("v_cvt_pk_bf16_f32 %0, %1, %2" : "=v"(r) : "v"(lo), "v"(hi));
    return r;
}
DEVI void pl32(uint32_t &a, uint32_t &b) {
    const uint32x2 r = __builtin_amdgcn_permlane32_swap(a, b, false, false);
    a = r[0]; b = r[1];
}

// ============================================================
__global__ void sniff_kernel(const uint16_t* __restrict__ x, int* __restrict__ flag)
{
    int bad = 0;
    for (int i = threadIdx.x; i < 512; i += 64) {
        const float v = bf1(x[i]);
        if (!(fabsf(v) < 64.0f)) bad = 1;
    }
    const unsigned long long m = __ballot(bad);
    if (threadIdx.x == 0) *flag = (m != 0ull) ? 1 : 0;
}

// ============================================================
__global__ __launch_bounds__(256)
void convert_kernel(const void* __restrict__ x, const void* __restrict__ Wq,
                    const void* __restrict__ Wk, const void* __restrict__ Wv,
                    const void* __restrict__ Wo, const void* __restrict__ bq,
                    const void* __restrict__ bk, const void* __restrict__ bv,
                    const void* __restrict__ bo, uint16_t* __restrict__ dst,
                    const int* __restrict__ flagp)
{
    const bool f32in = (*flagp != 0);
    const size_t M4 = 4194304, M1 = 1048576;
    const size_t e = ((size_t)blockIdx.x * 256 + threadIdx.x) * 8;
    const void* src; size_t off;
    if      (e < M4)                 { src = x;  off = e; }
    else if (e < M4 + M1)            { src = Wq; off = e - M4; }
    else if (e < M4 + 2*M1)          { src = Wk; off = e - M4 - M1; }
    else if (e < M4 + 3*M1)          { src = Wv; off = e - M4 - 2*M1; }
    else if (e < M4 + 4*M1)          { src = Wo; off = e - M4 - 3*M1; }
    else if (e < M4 + 4*M1 + 1024)   { src = bq; off = e - M4 - 4*M1; }
    else if (e < M4 + 4*M1 + 2048)   { src = bk; off = e - M4 - 4*M1 - 1024; }
    else if (e < M4 + 4*M1 + 3072)   { src = bv; off = e - M4 - 4*M1 - 2048; }
    else                             { src = bo; off = e - M4 - 4*M1 - 3072; }
    if (f32in) {
        const float4 a = *(const float4*)((const float*)src + off);
        const float4 b = *(const float4*)((const float*)src + off + 4);
        uint4 o;
        o.x = (uint32_t)f2bf(a.x) | ((uint32_t)f2bf(a.y) << 16);
        o.y = (uint32_t)f2bf(a.z) | ((uint32_t)f2bf(a.w) << 16);
        o.z = (uint32_t)f2bf(b.x) | ((uint32_t)f2bf(b.y) << 16);
        o.w = (uint32_t)f2bf(b.z) | ((uint32_t)f2bf(b.w) << 16);
        *(uint4*)(dst + e) = o;
    } else {
        *(uint4*)(dst + e) = *(const uint4*)((const uint16_t*)src + off);
    }
}

// ============================================================
// Fused QKV MFMA GEMM. Q output PRESCALED by 0.125*log2(e) so attention
// can use exp2 directly (saves one v_mul per score).
// ============================================================
__global__ __launch_bounds__(256)
void gemm_qkv(const uint16_t* __restrict__ xc, const uint16_t* __restrict__ Wqkv,
              const uint16_t* __restrict__ bqkv,
              uint16_t* __restrict__ Qw, uint16_t* __restrict__ Kw,
              uint16_t* __restrict__ Vt)
{
    __shared__ uint16_t As[128 * 32];
    __shared__ uint16_t Bs[128 * 32];
    const int tid = threadIdx.x, bx = blockIdx.x;
    const int lane = tid & 63, wave = tid >> 6;
    const int ln = lane & 15, quad = lane >> 4;
    const int wm = (wave & 1) * 64, wn = (wave >> 1) * 64;

    const uint16_t *Ab, *Bb;
    int bm, bn, vor;
    if (bx < 512) {
        vor = 0; bm = (bx >> 4) * 128; bn = (bx & 15) * 128;
        Ab = xc + (size_t)bm * DM;  Bb = Wqkv + (size_t)bn * DM;
    } else {
        vor = 1; const int b2 = bx - 512; bm = (b2 >> 5) * 128; bn = (b2 & 31) * 128;
        Ab = Wqkv + (size_t)(2048 + bm) * DM;  Bb = xc + (size_t)bn * DM;
    }

    f32x4 acc[4][4];
    #pragma unroll
    for (int i = 0; i < 4; ++i)
        #pragma unroll
        for (int j = 0; j < 4; ++j) acc[i][j] = (f32x4){0.f, 0.f, 0.f, 0.f};

    const int s0 = tid, s1 = 256 + tid;
    const uint16_t* ga0 = Ab + (size_t)(s0 >> 2) * DM + (s0 & 3) * 8;
    const uint16_t* ga1 = Ab + (size_t)(s1 >> 2) * DM + (s1 & 3) * 8;
    const uint16_t* gb0 = Bb + (size_t)(s0 >> 2) * DM + (s0 & 3) * 8;
    const uint16_t* gb1 = Bb + (size_t)(s1 >> 2) * DM + (s1 & 3) * 8;

    for (int k0 = 0; k0 < DM; k0 += 32) {
        __syncthreads();
        gld16(ga0 + k0, &As[s0 * 8]);
        gld16(ga1 + k0, &As[s1 * 8]);
        gld16(gb0 + k0, &Bs[s0 * 8]);
        gld16(gb1 + k0, &Bs[s1 * 8]);
        __syncthreads();

        bf16x8 af[4], bfr[4];
        #pragma unroll
        for (int t = 0; t < 4; ++t) {
            af[t]  = ld_frag(&As[(wm + t * 16 + ln) * 32 + quad * 8]);
            bfr[t] = ld_frag(&Bs[(wn + t * 16 + ln) * 32 + quad * 8]);
        }
        #pragma unroll
        for (int ti = 0; ti < 4; ++ti)
            #pragma unroll
            for (int tj = 0; tj < 4; ++tj)
                acc[ti][tj] = MFMA16(af[ti], bfr[tj], acc[ti][tj]);
    }

    if (!vor) {
        #pragma unroll
        for (int tj = 0; tj < 4; ++tj) {
            const int c = bn + wn + tj * 16 + ln;
            const int mat = c >> 10, h = (c >> 6) & 15, hd = c & 63;
            uint16_t* dstp = mat ? Kw : Qw;
            const float scale = mat ? 1.0f : (0.125f * LOG2E);
            const float bb = bf1(bqkv[c]);
            #pragma unroll
            for (int ti = 0; ti < 4; ++ti)
                #pragma unroll
                for (int r = 0; r < 4; ++r) {
                    const int row = bm + wm + ti * 16 + quad * 4 + r;
                    const int b = row >> 11, s = row & 2047;
                    dstp[(((size_t)b * NH + h) * SEQ + s) * HD + hd] =
                        f2bf((acc[ti][tj][r] + bb) * scale);
                }
        }
    } else {
        #pragma unroll
        for (int ti = 0; ti < 4; ++ti)
            #pragma unroll
            for (int r = 0; r < 4; ++r) {
                const int f = bm + wm + ti * 16 + quad * 4 + r;
                const int h = f >> 6, hd = f & 63;
                const float bb = bf1(bqkv[2048 + f]);
                #pragma unroll
                for (int tj = 0; tj < 4; ++tj) {
                    const int t = bn + wn + tj * 16 + ln;
                    const int b = t >> 11, s = t & 2047;
                    Vt[(((size_t)b * NH + h) * HD + hd) * SEQ + s] = f2bf(acc[ti][tj][r] + bb);
                }
            }
    }
}

// ============================================================
// Output projection: out = Cw · Woc^T + bo. 128x64 tiles -> 512 blocks.
// ============================================================
__global__ __launch_bounds__(256)
void gemm_out(const uint16_t* __restrict__ Cw, const uint16_t* __restrict__ Woc,
              const uint16_t* __restrict__ boc, void* __restrict__ out,
              const int* __restrict__ flagp)
{
    __shared__ uint16_t As[128 * 32];
    __shared__ uint16_t Bs[64 * 32];
    const int tid = threadIdx.x, bx = blockIdx.x;
    const int lane = tid & 63, wave = tid >> 6;
    const int ln = lane & 15, quad = lane >> 4;
    const int wm = (wave & 1) * 64, wn = (wave >> 1) * 32;
    const int bm = (bx >> 4) * 128, bn = (bx & 15) * 64;
    const uint16_t* Ab = Cw + (size_t)bm * DM;
    const uint16_t* Bb = Woc + (size_t)bn * DM;

    f32x4 acc[4][2];
    #pragma unroll
    for (int i = 0; i < 4; ++i)
        #pragma unroll
        for (int j = 0; j < 2; ++j) acc[i][j] = (f32x4){0.f, 0.f, 0.f, 0.f};

    const int s0 = tid, s1 = 256 + tid;
    const uint16_t* ga0 = Ab + (size_t)(s0 >> 2) * DM + (s0 & 3) * 8;
    const uint16_t* ga1 = Ab + (size_t)(s1 >> 2) * DM + (s1 & 3) * 8;
    const uint16_t* gb0 = Bb + (size_t)(s0 >> 2) * DM + (s0 & 3) * 8;

    for (int k0 = 0; k0 < DM; k0 += 32) {
        __syncthreads();
        gld16(ga0 + k0, &As[s0 * 8]);
        gld16(ga1 + k0, &As[s1 * 8]);
        gld16(gb0 + k0, &Bs[s0 * 8]);
        __syncthreads();

        bf16x8 af[4], bfr[2];
        #pragma unroll
        for (int t = 0; t < 4; ++t)
            af[t] = ld_frag(&As[(wm + t * 16 + ln) * 32 + quad * 8]);
        #pragma unroll
        for (int t = 0; t < 2; ++t)
            bfr[t] = ld_frag(&Bs[(wn + t * 16 + ln) * 32 + quad * 8]);
        #pragma unroll
        for (int ti = 0; ti < 4; ++ti)
            #pragma unroll
            for (int tj = 0; tj < 2; ++tj)
                acc[ti][tj] = MFMA16(af[ti], bfr[tj], acc[ti][tj]);
    }

    const bool f32o = (*flagp != 0);
    #pragma unroll
    for (int tj = 0; tj < 2; ++tj) {
        const int c = bn + wn + tj * 16 + ln;
        const float bb = bf1(boc[c]);
        #pragma unroll
        for (int ti = 0; ti < 4; ++ti)
            #pragma unroll
            for (int r = 0; r < 4; ++r) {
                const int row = bm + wm + ti * 16 + quad * 4 + r;
                const float v = acc[ti][tj][r] + bb;
                if (f32o) ((float*)out)[(size_t)row * DM + c] = v;
                else      ((uint16_t*)out)[(size_t)row * DM + c] = f2bf(v);
            }
    }
}

// ============================================================
// Flash-style MFMA attention v13 = v12b structure (PROVEN green:
// MFMA32 swapped QK^T, in-register P, diag bias, epilogue) with P_BUILD
// re-accelerated via the guide-verified T12 primitives:
//   - asm v_cvt_pk_bf16_f32 (16/phase) replaces scalar RTNE packing
//   - BUILTIN __builtin_amdgcn_permlane32_swap (8/phase) replaces the
//     16 __shfl_xor LDS-ops + 16 selects. pl32(c0,c2)... reproduces
//     exactly v12b's green lane mapping (paper-verified):
//       new_c0 = lanes<32: own c0 ; lanes>=32: c2[lane-32]
//       new_c2 = lanes<32: c0[lane+32] ; lanes>=32: own c2
// v12's failure is attributed to the hand-rolled in-place permlane ASM
// (the only non-recipe primitive); if this round fails absmax~2.88 the
// cvt_pk asm is the true culprit -> revert cvt_pk only.
// ============================================================
#define P_BUILD(SA, PA_LO, PA_HI)                                              \
  do {                                                                         \
    uint32_t c0_ = cvt_pk_bf16((SA)[0], (SA)[1]);                              \
    uint32_t c1_ = cvt_pk_bf16((SA)[2], (SA)[3]);                              \
    uint32_t c2_ = cvt_pk_bf16((SA)[4], (SA)[5]);                              \
    uint32_t c3_ = cvt_pk_bf16((SA)[6], (SA)[7]);                              \
    uint32_t c4_ = cvt_pk_bf16((SA)[8], (SA)[9]);                              \
    uint32_t c5_ = cvt_pk_bf16((SA)[10], (SA)[11]);                            \
    uint32_t c6_ = cvt_pk_bf16((SA)[12], (SA)[13]);                            \
    uint32_t c7_ = cvt_pk_bf16((SA)[14], (SA)[15]);                            \
    pl32(c0_, c2_); pl32(c1_, c3_);                                            \
    pl32(c4_, c6_); pl32(c5_, c7_);                                            \
    union { uint32_t u[4]; bf16x8 f; } lo_, hi_;                               \
    lo_.u[0] = c0_; lo_.u[1] = c1_; lo_.u[2] = c2_; lo_.u[3] = c3_;            \
    hi_.u[0] = c4_; hi_.u[1] = c5_; hi_.u[2] = c6_; hi_.u[3] = c7_;            \
    (PA_LO) = lo_.f; (PA_HI) = hi_.f;                                          \
  } while (0)

#define ATTN_COMPUTE(K0, KSB, VSB)                                             \
  do {                                                                         \
    const int mode_ = ((K0) >= q0 + 256) ? 0 : (((K0) + 192 <= q0) ? 2 : 1);   \
    bf16x8 kf_[2][4], vf_[2][4];                                               \
    _Pragma("unroll")                                                          \
    for (int kb = 0; kb < 2; ++kb)                                             \
      _Pragma("unroll")                                                        \
      for (int ds = 0; ds < 4; ++ds)                                           \
        kf_[kb][ds] = ld_frag((KSB) + kfo[kb][ds]);                            \
    _Pragma("unroll")                                                          \
    for (int db = 0; db < 2; ++db)                                             \
      _Pragma("unroll")                                                        \
      for (int kc = 0; kc < 4; ++kc)                                           \
        vf_[db][kc] = ld_frag((VSB) + vfo[db][kc]);                            \
    f32x16 sa0, sa1;                                                           \
    {                                                                          \
      const float binit_ = (mode_ == 0) ? bneg : ((mode_ == 2) ? bpos : 0.f);  \
      _Pragma("unroll")                                                        \
      for (int r = 0; r < 16; ++r) { sa0[r] = binit_; sa1[r] = binit_; }       \
    }                                                                          \
    _Pragma("unroll")                                                          \
    for (int ds = 0; ds < 4; ++ds) {                                           \
      sa0 = MFMA32(kf_[0][ds], qb[ds], sa0);                                   \
      sa1 = MFMA32(kf_[1][ds], qb[ds], sa1);                                   \
    }                                                                          \
    if (mode_ == 1) {                                                          \
      const int iq0_ = q0 + wave * 32 + l31 + 128 - (K0) - 4 * hi;             \
      _Pragma("unroll")                                                        \
      for (int r = 0; r < 16; ++r) {                                           \
        const int ko_ = (r & 3) + 8 * (r >> 2);                                \
        const int x0_ = max(0, min(256, iq0_ - ko_));                          \
        const int x1_ = max(0, min(256, iq0_ - 32 - ko_));                     \
        sa0[r] += bias_s[x0_];                                                 \
        sa1[r] += bias_s[x1_];                                                 \
      }                                                                        \
    }                                                                          \
    _Pragma("unroll")                                                          \
    for (int r = 0; r < 16; ++r) {                                             \
      sa0[r] = __builtin_amdgcn_exp2f(sa0[r]);                                 \
      sa1[r] = __builtin_amdgcn_exp2f(sa1[r]);                                 \
    }                                                                          \
    bf16x8 pa_[4];                                                             \
    P_BUILD(sa0, pa_[0], pa_[1]);                                              \
    P_BUILD(sa1, pa_[2], pa_[3]);                                              \
    _Pragma("unroll")                                                          \
    for (int kc = 0; kc < 4; ++kc) {                                           \
      lf    = MFMA32(pa_[kc], onef, lf);                                       \
      o2[0] = MFMA32(pa_[kc], vf_[0][kc], o2[0]);                              \
      o2[1] = MFMA32(pa_[kc], vf_[1][kc], o2[1]);                              \
    }                                                                          \
  } while (0)

__global__ __launch_bounds__(256, 2)
void attn_mfma(const uint16_t* __restrict__ Q, const uint16_t* __restrict__ K,
               const uint16_t* __restrict__ Vt, const void* __restrict__ rel,
               uint16_t* __restrict__ ctx, const int* __restrict__ flagp)
{
    __shared__ alignas(16) uint16_t Ks[2][64 * 64];   // [buf][key][d], swizzled, 16 KB
    __shared__ alignas(16) uint16_t Vls[2][64 * 64];  // [buf][d][key], swizzled, 16 KB
    __shared__ float bias_s[NBUCKET];                 // bias*log2e - C8

    const bool f32in = (*flagp != 0);
    const int tid = threadIdx.x, wave = tid >> 6, lane = tid & 63;
    const int l31 = lane & 31, hi = lane >> 5;

    const int blk = blockIdx.x;                         // 512 blocks
    const int bh = (blk & 7) * 4 + ((blk >> 3) & 3);    // XCD-aware bh spread
    const int qt = blk >> 5;                            // 16 q-tiles of 128 rows
    const int b = bh >> 4, h = bh & 15;
    const int q0 = qt * 128;

    const float C8 = 8.0f * LOG2E;   // fixed-max shift (in exp2 domain)
    for (int i = tid; i < NBUCKET; i += 256) {
        const float bv = f32in ? ((const float*)rel)[i * NH + h]
                               : bf1(((const uint16_t*)rel)[i * NH + h]);
        bias_s[i] = bv * LOG2E - C8;
    }

    // Q B-frags (32x32x16 B-layout): lane holds col q = l31, k = hi*8+j
    bf16x8 qb[4];
    {
        const uint16_t* qp = Q + ((size_t)bh * SEQ + q0 + wave * 32 + l31) * HD;
        #pragma unroll
        for (int ds = 0; ds < 4; ++ds)
            qb[ds] = ld_frag(qp + ds * 16 + hi * 8);
    }

    // ones B-frag for l = P · 1 (reads the same bf16 pa frags as PV)
    union { uint4 u; bf16x8 f; } onec;
    onec.u = (uint4){0x3F803F80u, 0x3F803F80u, 0x3F803F80u, 0x3F803F80u};
    const bf16x8 onef = onec.f;

    f32x16 o2[2], lf;
    #pragma unroll
    for (int r = 0; r < 16; ++r) { o2[0][r] = 0.f; o2[1][r] = 0.f; lf[r] = 0.f; }

    // ---- staging: 256 threads x 2 segments x 16 B = one 64x128B tile ----
    const int s0_ = tid, s1_ = tid + 256;
    const int r0_ = s0_ >> 3, c0s_ = (s0_ & 7) ^ (r0_ & 7);
    const int r1_ = s1_ >> 3, c1s_ = (s1_ & 7) ^ (r1_ & 7);
    const int koff0 = r0_ * HD + c0s_ * 8,  koff1 = r1_ * HD + c1s_ * 8;
    const int voff0 = r0_ * SEQ + c0s_ * 8, voff1 = r1_ * SEQ + c1s_ * 8;
    uint16_t* const kd00 = &Ks[0][s0_ * 8];
    uint16_t* const kd01 = &Ks[0][s1_ * 8];
    uint16_t* const kd10 = &Ks[1][s0_ * 8];
    uint16_t* const kd11 = &Ks[1][s1_ * 8];
    uint16_t* const vd00 = &Vls[0][s0_ * 8];
    uint16_t* const vd01 = &Vls[0][s1_ * 8];
    uint16_t* const vd10 = &Vls[1][s0_ * 8];
    uint16_t* const vd11 = &Vls[1][s1_ * 8];

    const uint16_t* kg = K  + (size_t)bh * SEQ * HD;   // +64*HD per tile
    const uint16_t* vg = Vt + (size_t)bh * HD * SEQ;   // +64 per tile

    // ---- k0-invariant LDS frag offsets (row&7 == l31&7 for both) ----
    const int swz = l31 & 7;
    int kfo[2][4], vfo[2][4];
    #pragma unroll
    for (int kb = 0; kb < 2; ++kb)
        #pragma unroll
        for (int ds = 0; ds < 4; ++ds)
            kfo[kb][ds] = (kb * 32 + l31) * 64 + ((ds * 2 + hi) ^ swz) * 8;
    #pragma unroll
    for (int db = 0; db < 2; ++db)
        #pragma unroll
        for (int kc = 0; kc < 4; ++kc)
            vfo[db][kc] = (db * 32 + l31) * 64 + ((kc * 2 + hi) ^ swz) * 8;

    // ---- prologue: stage tile 0 into buf0 ----
    gld16(kg + koff0, kd00); gld16(kg + koff1, kd01);
    gld16(vg + voff0, vd00); gld16(vg + voff1, vd01);
    kg += 64 * HD; vg += 64;
    __syncthreads();   // drains stage-0 + bias_s fill
    const float bneg = bias_s[0], bpos = bias_s[256];

    // ---- main loop: 16 double-iters, 1 barrier per k-tile ----
    for (int t = 0; t < 16; ++t) {
        // phase A: tile 2t in buf0; prefetch tile 2t+1 -> buf1
        gld16(kg + koff0, kd10); gld16(kg + koff1, kd11);
        gld16(vg + voff0, vd10); gld16(vg + voff1, vd11);
        kg += 64 * HD; vg += 64;
        ATTN_COMPUTE(t * 128, &Ks[0][0], &Vls[0][0]);
        __syncthreads();   // vmcnt(0) drain lands ~full phase after issue

        // phase B: tile 2t+1 in buf1; prefetch tile 2t+2 -> buf0
        if (t < 15) {
            gld16(kg + koff0, kd00); gld16(kg + koff1, kd01);
            gld16(vg + voff0, vd00); gld16(vg + voff1, vd01);
            kg += 64 * HD; vg += 64;
        }
        ATTN_COMPUTE(t * 128 + 64, &Ks[1][0], &Vls[1][0]);
        __syncthreads();
    }

    // ---- epilogue: lf[r] and o2[db][r] share the q=crow(r,hi) layout ----
    #pragma unroll
    for (int r = 0; r < 16; ++r) {
        const float inv = 1.0f / lf[r];
        const int qq = q0 + wave * 32 + (r & 3) + 8 * (r >> 2) + 4 * hi;
        #pragma unroll
        for (int db = 0; db < 2; ++db)
            ctx[(((size_t)b * SEQ + qq) * NH + h) * HD + db * 32 + l31] =
                f2bf(o2[db][r] * inv);
    }
}

// ============================================================
extern "C" void kernel_launch(void* const* d_in, const int* in_sizes, int n_in,
                              void* d_out, int out_size, void* d_ws, size_t ws_size,
                              hipStream_t stream)
{
    const void* x   = d_in[0];
    const void* Wq  = d_in[1];
    const void* bq  = d_in[2];
    const void* Wk  = d_in[3];
    const void* bk  = d_in[4];
    const void* Wv  = d_in[5];
    const void* bv  = d_in[6];
    const void* Wo  = d_in[7];
    const void* bo  = d_in[8];
    const void* rel = d_in[9];

    const size_t M4 = 4194304, M1 = 1048576;
    uint16_t* ws16 = (uint16_t*)d_ws;
    uint16_t* xc   = ws16;                    // 4M; reused as Cw after QKV GEMM
    uint16_t* Wqkv = ws16 + M4;               // 3M  [Wq;Wk;Wv]
    uint16_t* Woc  = ws16 + M4 + 3 * M1;      // 1M
    uint16_t* bqkv = ws16 + M4 + 4 * M1;      // 3072 [bq;bk;bv]
    uint16_t* boc  = bqkv + 3072;             // 1024
    uint16_t* Qw   = ws16 + M4 + 4 * M1 + 8192;
    uint16_t* Kw   = Qw + M4;
    uint16_t* Vt   = Kw + M4;
    int* flag = (int*)(Vt + M4);
    uint16_t* Cw = xc;   // overlay: xc dead after gemm_qkv

    sniff_kernel<<<1, 64, 0, stream>>>((const uint16_t*)x, flag);
    convert_kernel<<<4098, 256, 0, stream>>>(x, Wq, Wk, Wv, Wo, bq, bk, bv, bo,
                                             ws16, flag);
    gemm_qkv<<<768, 256, 0, stream>>>(xc, Wqkv, bqkv, Qw, Kw, Vt);
    attn_mfma<<<512, 256, 0, stream>>>(Qw, Kw, Vt, rel, Cw, flag);
    gemm_out<<<512, 256, 0, stream>>>(Cw, Woc, boc, d_out, flag);
}